// Round 2
// baseline (10696.806 us; speedup 1.0000x reference)
//
#include <hip/hip_runtime.h>
#include <math.h>

// ---------------- problem constants ----------------
#define NB   128          // batch
#define DC   256          // channel dim D (= 2*NH)
#define SP   256          // 16*16 spatial
#define NROW 32768        // NB * 16 * 16
#define KCB  1024         // codebook size
#define BETA_F 0.1f
#define EPSQ 1e-10f

// =====================================================================
// 4x4 stride-2 conv (+bias+relu). block=256 thr (16x16 pixels), 8 couts/thr
// grid: (cout/8, tiles*tiles, B)
// =====================================================================
__global__ __launch_bounds__(256) void conv4s2_kernel(
    const float* __restrict__ in, const float* __restrict__ wt,
    const float* __restrict__ bias, float* __restrict__ out,
    int cin, int cout, int hin, int hout, int tiles)
{
  const int tid = threadIdx.x;
  const int tx = tid & 15, ty = tid >> 4;
  const int cog = blockIdx.x;
  const int tile = blockIdx.y;
  const int b = blockIdx.z;
  const int ow = (tile % tiles) * 16 + tx;
  const int oh = (tile / tiles) * 16 + ty;
  const int co0 = cog * 8;

  float acc[8];
#pragma unroll
  for (int g = 0; g < 8; ++g) acc[g] = 0.f;

  const float* inb = in + (size_t)b * cin * hin * hin;
  for (int ci = 0; ci < cin; ++ci) {
    const float* p = inb + (size_t)ci * hin * hin;
    const float* wb = wt + ((size_t)co0 * cin + ci) * 16;
#pragma unroll
    for (int kh = 0; kh < 4; ++kh) {
      const int ih = oh * 2 + kh - 1;
      if (ih < 0 || ih >= hin) continue;
#pragma unroll
      for (int kw = 0; kw < 4; ++kw) {
        const int iw = ow * 2 + kw - 1;
        if (iw < 0 || iw >= hin) continue;
        const float v = p[ih * hin + iw];
#pragma unroll
        for (int g = 0; g < 8; ++g)
          acc[g] = fmaf(wb[(size_t)g * cin * 16 + kh * 4 + kw], v, acc[g]);
      }
    }
  }
  const size_t ob = ((size_t)(b * cout + co0) * hout + oh) * hout + ow;
#pragma unroll
  for (int g = 0; g < 8; ++g) {
    float r = acc[g] + bias[co0 + g];
    out[ob + (size_t)g * hout * hout] = fmaxf(r, 0.f);
  }
}

// =====================================================================
// 3x3 pad-1 conv, C=256, 16x16, +bias, optional residual, relu always.
// block=256 thr (one 16x16 plane), 8 couts/thr. grid: (32, B)
// =====================================================================
__global__ __launch_bounds__(256) void conv3x3_kernel(
    const float* __restrict__ in, const float* __restrict__ wt,
    const float* __restrict__ bias, const float* __restrict__ res,
    float* __restrict__ out)
{
  const int tid = threadIdx.x;
  const int pw = tid & 15, ph = tid >> 4;
  const int cog = blockIdx.x;
  const int b = blockIdx.y;
  const int co0 = cog * 8;

  float acc[8];
#pragma unroll
  for (int g = 0; g < 8; ++g) acc[g] = 0.f;

  const bool hm = ph > 0, hp = ph < 15, wm = pw > 0, wp = pw < 15;
  const float* inb = in + (size_t)b * DC * SP + ph * 16 + pw;
  const float* wb = wt + (size_t)co0 * DC * 9;

  for (int ci = 0; ci < DC; ++ci) {
    const float* p = inb + ci * SP;
    float v[9];
    v[0] = (hm && wm) ? p[-17] : 0.f;
    v[1] = hm ? p[-16] : 0.f;
    v[2] = (hm && wp) ? p[-15] : 0.f;
    v[3] = wm ? p[-1] : 0.f;
    v[4] = p[0];
    v[5] = wp ? p[1] : 0.f;
    v[6] = (hp && wm) ? p[15] : 0.f;
    v[7] = hp ? p[16] : 0.f;
    v[8] = (hp && wp) ? p[17] : 0.f;
#pragma unroll
    for (int g = 0; g < 8; ++g) {
      const float* wr = wb + (size_t)g * DC * 9 + ci * 9;
#pragma unroll
      for (int j = 0; j < 9; ++j) acc[g] = fmaf(wr[j], v[j], acc[g]);
    }
  }
  const size_t ob = (size_t)(b * DC + co0) * SP + ph * 16 + pw;
#pragma unroll
  for (int g = 0; g < 8; ++g) {
    float r = acc[g] + bias[co0 + g];
    if (res) r += res[ob + (size_t)g * SP];
    out[ob + (size_t)g * SP] = fmaxf(r, 0.f);
  }
}

// =====================================================================
// zf[n][d] = z[b][d][h][w],  n = b*256 + h*16+w
// =====================================================================
__global__ void zf_kernel(const float* __restrict__ z, float* __restrict__ zf)
{
  const int n = blockIdx.x;
  const int d = threadIdx.x;
  const int b = n >> 8, hw = n & 255;
  zf[(size_t)n * DC + d] = z[((size_t)(b * DC + d)) * SP + hw];
}

// row squared-norms over dim 256; one wave per row (4 rows per block)
__global__ __launch_bounds__(256) void rownorm_kernel(
    const float* __restrict__ a, float* __restrict__ nrm, int rows)
{
  const int wv = threadIdx.x >> 6, lane = threadIdx.x & 63;
  const int r = blockIdx.x * 4 + wv;
  if (r >= rows) return;
  const float* p = a + (size_t)r * DC;
  float s = 0.f;
#pragma unroll
  for (int i = 0; i < 4; ++i) { float v = p[lane + 64 * i]; s = fmaf(v, v, s); }
#pragma unroll
  for (int o = 32; o > 0; o >>= 1) s += __shfl_xor(s, o);
  if (lane == 0) nrm[r] = s;
}

// =====================================================================
// distance GEMM: D[m][n] = zn[m] + cn[n] - 2 * zf[m,:]·cb[n,:]
// BM=BN=64, BK=32, 256 thr, 4x4 per thread.  grid (512, 16)
// =====================================================================
__global__ __launch_bounds__(256) void dist_kernel(
    const float* __restrict__ A, const float* __restrict__ Bc,
    const float* __restrict__ zn, const float* __restrict__ cn,
    float* __restrict__ D)
{
  __shared__ float As[32][66];
  __shared__ float Bs[32][66];
  const int tid = threadIdx.x;
  const int m0 = blockIdx.x * 64;
  const int n0 = blockIdx.y * 64;
  const int tm = tid >> 4, tn = tid & 15;
  float acc[4][4];
#pragma unroll
  for (int i = 0; i < 4; ++i)
#pragma unroll
    for (int j = 0; j < 4; ++j) acc[i][j] = 0.f;

  for (int k0 = 0; k0 < DC; k0 += 32) {
#pragma unroll
    for (int i = 0; i < 8; ++i) {
      const int idx = tid + i * 256;
      const int r = idx >> 5, kk = idx & 31;
      As[kk][r] = A[(size_t)(m0 + r) * DC + k0 + kk];
      Bs[kk][r] = Bc[(size_t)(n0 + r) * DC + k0 + kk];
    }
    __syncthreads();
#pragma unroll
    for (int kk = 0; kk < 32; ++kk) {
      float av[4], bv[4];
#pragma unroll
      for (int i = 0; i < 4; ++i) av[i] = As[kk][tm * 4 + i];
#pragma unroll
      for (int j = 0; j < 4; ++j) bv[j] = Bs[kk][tn * 4 + j];
#pragma unroll
      for (int i = 0; i < 4; ++i)
#pragma unroll
        for (int j = 0; j < 4; ++j) acc[i][j] = fmaf(av[i], bv[j], acc[i][j]);
    }
    __syncthreads();
  }
#pragma unroll
  for (int i = 0; i < 4; ++i) {
    const int m = m0 + tm * 4 + i;
    const float zni = zn[m];
#pragma unroll
    for (int j = 0; j < 4; ++j) {
      const int n = n0 + tn * 4 + j;
      D[(size_t)m * KCB + n] = zni + cn[n] - 2.f * acc[i][j];
    }
  }
}

// init logq from pi; zero qsum and Sacc (replaces hipMemsetAsync)
__global__ void initq_kernel(const float* __restrict__ pi, float* __restrict__ logq,
                             float* __restrict__ qsum, float* __restrict__ Sacc)
{
  const int k = blockIdx.x * 256 + threadIdx.x;
  logq[k] = logf(fmaxf(pi[k], EPSQ));
  qsum[k] = 0.f;
  if (k == 0) *Sacc = 0.f;
}

// =====================================================================
// one BA iteration: per row softmax(logq - beta*d) ; accumulate qsum.
// block=256 thr = 4 waves, 4 rows per wave (16 rows/block). grid 2048.
// storeP: write P in-place over D and argmax -> idxout.
// =====================================================================
__global__ __launch_bounds__(256) void ba_kernel(
    float* __restrict__ D, const float* __restrict__ logq,
    float* __restrict__ qsum, int* __restrict__ idxout, int storeP)
{
  __shared__ float qp[4][1024];
  const int tid = threadIdx.x;
  const int wv = tid >> 6, lane = tid & 63;
  for (int i = tid; i < 4096; i += 256) ((float*)qp)[i] = 0.f;
  __syncthreads();

  float lq[16];
#pragma unroll
  for (int it = 0; it < 16; ++it) lq[it] = logq[it * 64 + lane];

  const int n0 = blockIdx.x * 16;
  for (int rr = 0; rr < 4; ++rr) {
    const int n = n0 + wv * 4 + rr;
    float* drow = D + (size_t)n * KCB;
    float l[16];
    float mx = -1e30f;
#pragma unroll
    for (int it = 0; it < 16; ++it) {
      l[it] = lq[it] - BETA_F * drow[it * 64 + lane];
      mx = fmaxf(mx, l[it]);
    }
#pragma unroll
    for (int o = 32; o > 0; o >>= 1) mx = fmaxf(mx, __shfl_xor(mx, o));
    float e[16];
    float s = 0.f;
#pragma unroll
    for (int it = 0; it < 16; ++it) { e[it] = __expf(l[it] - mx); s += e[it]; }
#pragma unroll
    for (int o = 32; o > 0; o >>= 1) s += __shfl_xor(s, o);
    const float inv = 1.f / s;
#pragma unroll
    for (int it = 0; it < 16; ++it) qp[wv][it * 64 + lane] += e[it] * inv;

    if (storeP) {
#pragma unroll
      for (int it = 0; it < 16; ++it) drow[it * 64 + lane] = e[it] * inv;
      // argmax of logits == argmax of P; first index on ties
      float bv = l[0]; int bi = lane;
#pragma unroll
      for (int it = 1; it < 16; ++it) {
        const int k = it * 64 + lane;
        if (l[it] > bv) { bv = l[it]; bi = k; }
      }
#pragma unroll
      for (int o = 32; o > 0; o >>= 1) {
        const float ov = __shfl_xor(bv, o);
        const int oi = __shfl_xor(bi, o);
        if (ov > bv || (ov == bv && oi < bi)) { bv = ov; bi = oi; }
      }
      if (lane == 0) idxout[n] = bi;
    }
  }
  __syncthreads();
  for (int k = tid; k < 1024; k += 256) {
    const float v = qp[0][k] + qp[1][k] + qp[2][k] + qp[3][k];
    atomicAdd(&qsum[k], v);
  }
}

// Q = clip(qsum/N, eps); logq = log Q; re-zero qsum for next iteration
__global__ void finalize_kernel(float* __restrict__ qsum, float* __restrict__ logq)
{
  const int k = blockIdx.x * 256 + threadIdx.x;
  const float q = fmaxf(qsum[k] * (1.f / 32768.f), EPSQ);
  logq[k] = logf(q);
  qsum[k] = 0.f;
}

// ent_loss = 0.01 * sum(Q log Q) from final qsum ; single block 1024 thr
__global__ __launch_bounds__(1024) void ent_kernel(
    const float* __restrict__ qsum, float* __restrict__ out_ent)
{
  const int k = threadIdx.x;
  const float q = fmaxf(qsum[k] * (1.f / 32768.f), EPSQ);
  float v = q * logf(q);
#pragma unroll
  for (int o = 32; o > 0; o >>= 1) v += __shfl_xor(v, o);
  __shared__ float red[16];
  const int wv = k >> 6, lane = k & 63;
  if (lane == 0) red[wv] = v;
  __syncthreads();
  if (k == 0) {
    float s = 0.f;
    for (int i = 0; i < 16; ++i) s += red[i];
    *out_ent = 0.01f * s;
  }
}

// =====================================================================
// zq_soft = P @ cb ; accumulate sum((zq_soft - zf)^2) into Sacc.
// BM=BN=64, BK=32.  grid (512, 4)
// =====================================================================
__global__ __launch_bounds__(256) void zqloss_kernel(
    const float* __restrict__ P, const float* __restrict__ cb,
    const float* __restrict__ zf, float* __restrict__ Sacc)
{
  __shared__ float As[32][66];
  __shared__ float Bs[32][66];
  __shared__ float red[4];
  const int tid = threadIdx.x;
  const int m0 = blockIdx.x * 64;
  const int n0 = blockIdx.y * 64;
  const int tm = tid >> 4, tn = tid & 15;
  float acc[4][4];
#pragma unroll
  for (int i = 0; i < 4; ++i)
#pragma unroll
    for (int j = 0; j < 4; ++j) acc[i][j] = 0.f;

  for (int k0 = 0; k0 < KCB; k0 += 32) {
#pragma unroll
    for (int i = 0; i < 8; ++i) {
      const int idx = tid + i * 256;
      { const int r = idx >> 5, kk = idx & 31;
        As[kk][r] = P[(size_t)(m0 + r) * KCB + k0 + kk]; }
      { const int c = idx & 63, kk = idx >> 6;
        Bs[kk][c] = cb[(size_t)(k0 + kk) * DC + n0 + c]; }
    }
    __syncthreads();
#pragma unroll
    for (int kk = 0; kk < 32; ++kk) {
      float av[4], bv[4];
#pragma unroll
      for (int i = 0; i < 4; ++i) av[i] = As[kk][tm * 4 + i];
#pragma unroll
      for (int j = 0; j < 4; ++j) bv[j] = Bs[kk][tn * 4 + j];
#pragma unroll
      for (int i = 0; i < 4; ++i)
#pragma unroll
        for (int j = 0; j < 4; ++j) acc[i][j] = fmaf(av[i], bv[j], acc[i][j]);
    }
    __syncthreads();
  }
  float ls = 0.f;
#pragma unroll
  for (int i = 0; i < 4; ++i) {
    const int m = m0 + tm * 4 + i;
#pragma unroll
    for (int j = 0; j < 4; ++j) {
      const int n = n0 + tn * 4 + j;
      const float d = acc[i][j] - zf[(size_t)m * DC + n];
      ls = fmaf(d, d, ls);
    }
  }
#pragma unroll
  for (int o = 32; o > 0; o >>= 1) ls += __shfl_xor(ls, o);
  const int wv = tid >> 6, lane = tid & 63;
  if (lane == 0) red[wv] = ls;
  __syncthreads();
  if (tid == 0) atomicAdd(Sacc, red[0] + red[1] + red[2] + red[3]);
}

__global__ void scalars_kernel(const float* __restrict__ S, float* __restrict__ out2)
{
  const float s = *S;
  out2[0] = 0.25f * s / 8388608.f;  // commit
  out2[1] = s / 8388608.f;          // cb_loss
}

// zq_hard gather: zq[b][d][h][w] = cb[idx[n]][d]
__global__ void gather_kernel(const int* __restrict__ idx,
                              const float* __restrict__ cb, float* __restrict__ zq)
{
  const int bd = blockIdx.x;      // b*256+d
  const int b = bd >> 8, d = bd & 255;
  const int hw = threadIdx.x;
  const int n = b * 256 + hw;
  zq[(size_t)bd * SP + hw] = cb[(size_t)idx[n] * DC + d];
}

// =====================================================================
// ConvTranspose2d 256->128, k4 s2 p1, +bias+relu.  in 16x16 -> out 32x32.
// parity-split so weight indices are block-uniform. grid (64, 128)
// =====================================================================
__global__ __launch_bounds__(256) void convt2_kernel(
    const float* __restrict__ in, const float* __restrict__ wt,
    const float* __restrict__ bias, float* __restrict__ out)
{
  const int tid = threadIdx.x;
  const int x = tid & 15, y = tid >> 4;
  const int par = blockIdx.x & 3;
  const int cog = blockIdx.x >> 2;   // 0..15
  const int b = blockIdx.y;
  const int po = par >> 1, pq = par & 1;
  const int oh = 2 * y + po, ow = 2 * x + pq;
  const int co0 = cog * 8;
  const int kh0 = po ? 0 : 1, kw0 = pq ? 0 : 1;
  const int ih0 = (oh + 1 - kh0) >> 1, ih1 = ih0 - 1;
  const int iw0 = (ow + 1 - kw0) >> 1, iw1 = iw0 - 1;
  const bool v0 = (ih0 >= 0 && ih0 < 16), v1 = (ih1 >= 0 && ih1 < 16);
  const bool u0 = (iw0 >= 0 && iw0 < 16), u1 = (iw1 >= 0 && iw1 < 16);

  float acc[8];
#pragma unroll
  for (int g = 0; g < 8; ++g) acc[g] = 0.f;

  for (int ci = 0; ci < 256; ++ci) {
    const float* p = in + (size_t)(b * 256 + ci) * SP;
    const float a00 = (v0 && u0) ? p[ih0 * 16 + iw0] : 0.f;
    const float a01 = (v0 && u1) ? p[ih0 * 16 + iw1] : 0.f;
    const float a10 = (v1 && u0) ? p[ih1 * 16 + iw0] : 0.f;
    const float a11 = (v1 && u1) ? p[ih1 * 16 + iw1] : 0.f;
    const float* wr = wt + ((size_t)ci * 128 + co0) * 16;
#pragma unroll
    for (int g = 0; g < 8; ++g) {
      const float* wg = wr + g * 16;
      acc[g] = fmaf(wg[kh0 * 4 + kw0], a00,
               fmaf(wg[kh0 * 4 + kw0 + 2], a01,
               fmaf(wg[(kh0 + 2) * 4 + kw0], a10,
               fmaf(wg[(kh0 + 2) * 4 + kw0 + 2], a11, acc[g]))));
    }
  }
#pragma unroll
  for (int g = 0; g < 8; ++g) {
    const float r = acc[g] + bias[co0 + g];
    out[((size_t)(b * 128 + co0 + g) * 32 + oh) * 32 + ow] = fmaxf(r, 0.f);
  }
}

// =====================================================================
// ConvTranspose2d 128->3, k4 s2 p1, +bias (no relu). in 32x32 -> out 64x64.
// grid (16, 128): blockIdx.x = tile*4 + parity
// =====================================================================
__global__ __launch_bounds__(256) void convt3_kernel(
    const float* __restrict__ in, const float* __restrict__ wt,
    const float* __restrict__ bias, float* __restrict__ out)
{
  const int tid = threadIdx.x;
  const int x = tid & 15, y = tid >> 4;
  const int par = blockIdx.x & 3;
  const int tile = blockIdx.x >> 2;  // 0..3
  const int b = blockIdx.y;
  const int po = par >> 1, pq = par & 1;
  const int yy = (tile >> 1) * 16 + y;  // 0..31
  const int xx = (tile & 1) * 16 + x;
  const int oh = 2 * yy + po, ow = 2 * xx + pq;
  const int kh0 = po ? 0 : 1, kw0 = pq ? 0 : 1;
  const int ih0 = (oh + 1 - kh0) >> 1, ih1 = ih0 - 1;
  const int iw0 = (ow + 1 - kw0) >> 1, iw1 = iw0 - 1;
  const bool v0 = (ih0 >= 0 && ih0 < 32), v1 = (ih1 >= 0 && ih1 < 32);
  const bool u0 = (iw0 >= 0 && iw0 < 32), u1 = (iw1 >= 0 && iw1 < 32);

  float acc[3] = {0.f, 0.f, 0.f};
  for (int ci = 0; ci < 128; ++ci) {
    const float* p = in + (size_t)(b * 128 + ci) * 1024;
    const float a00 = (v0 && u0) ? p[ih0 * 32 + iw0] : 0.f;
    const float a01 = (v0 && u1) ? p[ih0 * 32 + iw1] : 0.f;
    const float a10 = (v1 && u0) ? p[ih1 * 32 + iw0] : 0.f;
    const float a11 = (v1 && u1) ? p[ih1 * 32 + iw1] : 0.f;
    const float* wr = wt + (size_t)ci * 48;  // [3][4][4]
#pragma unroll
    for (int g = 0; g < 3; ++g) {
      const float* wg = wr + g * 16;
      acc[g] = fmaf(wg[kh0 * 4 + kw0], a00,
               fmaf(wg[kh0 * 4 + kw0 + 2], a01,
               fmaf(wg[(kh0 + 2) * 4 + kw0], a10,
               fmaf(wg[(kh0 + 2) * 4 + kw0 + 2], a11, acc[g]))));
    }
  }
#pragma unroll
  for (int g = 0; g < 3; ++g)
    out[((size_t)(b * 3 + g) * 64 + oh) * 64 + ow] = acc[g] + bias[g];
}

// =====================================================================
extern "C" void kernel_launch(void* const* d_in, const int* in_sizes, int n_in,
                              void* d_out, int out_size, void* d_ws, size_t ws_size,
                              hipStream_t stream)
{
  const float* x     = (const float*)d_in[0];
  const float* ew1   = (const float*)d_in[1];
  const float* eb1   = (const float*)d_in[2];
  const float* ew2   = (const float*)d_in[3];
  const float* eb2   = (const float*)d_in[4];
  const float* ew3   = (const float*)d_in[5];
  const float* eb3   = (const float*)d_in[6];
  const float* er1aw = (const float*)d_in[7];
  const float* er1ab = (const float*)d_in[8];
  const float* er1bw = (const float*)d_in[9];
  const float* er1bb = (const float*)d_in[10];
  const float* er2aw = (const float*)d_in[11];
  const float* er2ab = (const float*)d_in[12];
  const float* er2bw = (const float*)d_in[13];
  const float* er2bb = (const float*)d_in[14];
  const float* cb    = (const float*)d_in[15];
  const float* pi    = (const float*)d_in[16];
  const float* dr1aw = (const float*)d_in[17];
  const float* dr1ab = (const float*)d_in[18];
  const float* dr1bw = (const float*)d_in[19];
  const float* dr1bb = (const float*)d_in[20];
  const float* dr2aw = (const float*)d_in[21];
  const float* dr2ab = (const float*)d_in[22];
  const float* dr2bw = (const float*)d_in[23];
  const float* dr2bb = (const float*)d_in[24];
  const float* dw1   = (const float*)d_in[25];
  const float* db1   = (const float*)d_in[26];
  const float* dwt2  = (const float*)d_in[27];
  const float* dbt2  = (const float*)d_in[28];
  const float* dwt3  = (const float*)d_in[29];
  const float* dbt3  = (const float*)d_in[30];

  float* outf = (float*)d_out;

  // workspace layout (floats) — 50,400,657 floats ~= 201.6 MB
  // BIG is time-shared: encoder h1 (16.7M) -> DIST/P (33.5M) -> decoder
  // y1 (8.4M, first part) -> convt2 output (16.7M).
  float* ws   = (float*)d_ws;
  float* BIG  = ws;                    // 33,554,432
  float* Bb   = BIG + 33554432;        //  8,388,608
  float* Cc   = Bb + 8388608;          //  8,388,608
  float* zn   = Cc + 8388608;          // 32,768
  float* cbn  = zn + 32768;            // 1,024
  float* qsum = cbn + 1024;            // 1,024
  float* logq = qsum + 1024;           // 1,024
  int*   idx  = (int*)(logq + 1024);   // 32,768 ints
  float* Sacc = (float*)(idx + 32768); // 1

  const dim3 blk(256);

  // -------- encoder --------
  conv4s2_kernel<<<dim3(16, 4, NB), blk, 0, stream>>>(x, ew1, eb1, BIG, 3, 128, 64, 32, 2);
  conv4s2_kernel<<<dim3(32, 1, NB), blk, 0, stream>>>(BIG, ew2, eb2, Bb, 128, 256, 32, 16, 1);
  conv3x3_kernel<<<dim3(32, NB), blk, 0, stream>>>(Bb, ew3, eb3, nullptr, Cc);    // h3
  conv3x3_kernel<<<dim3(32, NB), blk, 0, stream>>>(Cc, er1aw, er1ab, nullptr, BIG);
  conv3x3_kernel<<<dim3(32, NB), blk, 0, stream>>>(BIG, er1bw, er1bb, Cc, Bb);    // h4
  conv3x3_kernel<<<dim3(32, NB), blk, 0, stream>>>(Bb, er2aw, er2ab, nullptr, BIG);
  conv3x3_kernel<<<dim3(32, NB), blk, 0, stream>>>(BIG, er2bw, er2bb, Bb, Cc);    // z

  // -------- VQ / Blahut-Arimoto --------
  zf_kernel<<<dim3(NROW), blk, 0, stream>>>(Cc, Bb);                              // zf
  rownorm_kernel<<<dim3(NROW / 4), blk, 0, stream>>>(Bb, zn, NROW);
  rownorm_kernel<<<dim3(KCB / 4), blk, 0, stream>>>(cb, cbn, KCB);
  initq_kernel<<<dim3(4), blk, 0, stream>>>(pi, logq, qsum, Sacc);
  dist_kernel<<<dim3(NROW / 64, KCB / 64), blk, 0, stream>>>(Bb, cb, zn, cbn, BIG);
  for (int i = 0; i < 5; ++i) {
    ba_kernel<<<dim3(NROW / 16), blk, 0, stream>>>(BIG, logq, qsum, idx, (i == 4) ? 1 : 0);
    if (i < 4) finalize_kernel<<<dim3(4), blk, 0, stream>>>(qsum, logq);
  }
  ent_kernel<<<dim3(1), dim3(1024), 0, stream>>>(qsum, outf + 1572866);
  zqloss_kernel<<<dim3(NROW / 64, DC / 64), blk, 0, stream>>>(BIG, cb, Bb, Sacc);
  scalars_kernel<<<dim3(1), dim3(1), 0, stream>>>(Sacc, outf + 1572864);
  gather_kernel<<<dim3(NB * DC), blk, 0, stream>>>(idx, cb, Cc);                  // zq_hard

  // -------- decoder --------
  conv3x3_kernel<<<dim3(32, NB), blk, 0, stream>>>(Cc, dr1aw, dr1ab, nullptr, Bb);
  conv3x3_kernel<<<dim3(32, NB), blk, 0, stream>>>(Bb, dr1bw, dr1bb, Cc, BIG);    // y1
  conv3x3_kernel<<<dim3(32, NB), blk, 0, stream>>>(BIG, dr2aw, dr2ab, nullptr, Bb);
  conv3x3_kernel<<<dim3(32, NB), blk, 0, stream>>>(Bb, dr2bw, dr2bb, BIG, Cc);    // y2
  conv3x3_kernel<<<dim3(32, NB), blk, 0, stream>>>(Cc, dw1, db1, nullptr, Bb);
  convt2_kernel<<<dim3(64, NB), blk, 0, stream>>>(Bb, dwt2, dbt2, BIG);
  convt3_kernel<<<dim3(16, NB), blk, 0, stream>>>(BIG, dwt3, dbt3, outf);
}

// Round 4
// 2201.371 us; speedup vs baseline: 4.8592x; 4.8592x over previous
//
#include <hip/hip_runtime.h>
#include <math.h>

// ---------------- problem constants ----------------
#define NB   128
#define DC   256
#define SP   256
#define NROW 32768
#define KCB  1024
#define BETA_F 0.1f
#define EPSQ 1e-10f

typedef __attribute__((ext_vector_type(8))) short s16x8;
typedef __attribute__((ext_vector_type(4))) short s16x4;
typedef __attribute__((ext_vector_type(4))) float f32x4;

__device__ __forceinline__ short f2bf(float f) {
  unsigned u = __builtin_bit_cast(unsigned, f);
  unsigned r = (u + 0x7FFFu + ((u >> 16) & 1u)) >> 16;
  return (short)r;
}
__device__ __forceinline__ float bf2f(short s) {
  unsigned u = ((unsigned)(unsigned short)s) << 16;
  return __builtin_bit_cast(float, u);
}
__device__ __forceinline__ unsigned pack2(float a, float b) {
  return (unsigned)(unsigned short)f2bf(a) | ((unsigned)(unsigned short)f2bf(b) << 16);
}

// ========================= init: zero the zero-source buffer ===============
__global__ void init0_kernel(short* __restrict__ zerob)
{
  if (threadIdx.x < 8) zerob[threadIdx.x] = 0;
}

// ========================= weight transposes (fp32 -> bf16) =================
// conv3x3 [256co][256ci][3][3] -> [9][256co][256ci]
__global__ void w3t_kernel(const float* __restrict__ w, short* __restrict__ o)
{
  const int i = blockIdx.x * 256 + threadIdx.x;  // 589824
  const int ci = i & 255, co = (i >> 8) & 255, j = i >> 16;
  o[i] = f2bf(w[((size_t)(co * 256 + ci)) * 9 + j]);
}
// conv2 4x4 [256co][128ci][16] -> [16][256co][128ci]
__global__ void w2t_kernel(const float* __restrict__ w, short* __restrict__ o)
{
  const int i = blockIdx.x * 256 + threadIdx.x;  // 524288
  const int ci = i & 127, co = (i >> 7) & 255, j = i >> 15;
  o[i] = f2bf(w[((size_t)(co * 128 + ci)) * 16 + j]);
}
// convt2 [256ci][128co][4][4] -> [4 parity][4 tap][128co][256ci]
__global__ void wtt2_kernel(const float* __restrict__ w, short* __restrict__ o)
{
  const int i = blockIdx.x * 256 + threadIdx.x;  // 524288
  const int ci = i & 255, co = (i >> 8) & 127, j = (i >> 15) & 3, p = i >> 17;
  const int po = p >> 1, pq = p & 1, a = j >> 1, b2 = j & 1;
  const int kh = (1 - po) + 2 * a, kw = (1 - pq) + 2 * b2;
  o[i] = f2bf(w[((size_t)(ci * 128 + co)) * 16 + kh * 4 + kw]);
}
// codebook fp32 -> bf16 [1024][256]
__global__ void cbbf_kernel(const float* __restrict__ cb, short* __restrict__ o)
{
  const int i = blockIdx.x * 256 + threadIdx.x;  // 262144
  o[i] = f2bf(cb[i]);
}

// ========================= conv1: 3->128, 4x4 s2, 64->32, out NHWC bf16 =====
__global__ __launch_bounds__(256) void conv1_kernel(
    const float* __restrict__ x, const float* __restrict__ w,
    const float* __restrict__ bias, short* __restrict__ out)
{
  __shared__ float li[3][34][34];
  __shared__ __align__(16) float lw[6144];
  const int tid = threadIdx.x;
  const int tile = blockIdx.x;          // 0..3 quadrant of 32x32 output
  const int b = blockIdx.y;
  const int qy = tile >> 1, qx = tile & 1;
  const int ihlo = qy * 32 - 1, iwlo = qx * 32 - 1;
  for (int ci = 0; ci < 3; ++ci)
    for (int s = tid; s < 1156; s += 256) {
      const int r = s / 34, c = s - r * 34;
      const int ih = ihlo + r, iw = iwlo + c;
      float v = 0.f;
      if ((unsigned)ih < 64u && (unsigned)iw < 64u)
        v = x[((size_t)(b * 3 + ci) * 64 + ih) * 64 + iw];
      li[ci][r][c] = v;
    }
  for (int s = tid; s < 6144; s += 256) lw[s] = w[s];
  __syncthreads();
  const int ty = tid >> 4, tx = tid & 15;
  f32x4 tvq[12];
#pragma unroll
  for (int ci = 0; ci < 3; ++ci)
#pragma unroll
    for (int kh = 0; kh < 4; ++kh)
#pragma unroll
      for (int kw = 0; kw < 4; ++kw)
        tvq[ci * 4 + kh][kw] = li[ci][2 * ty + kh][2 * tx + kw];
  const int oh = qy * 16 + ty, ow = qx * 16 + tx;
  unsigned* orow = (unsigned*)(out + ((size_t)b * 1024 + oh * 32 + ow) * 128);
  float prev = 0.f;
  for (int co = 0; co < 128; ++co) {
    const f32x4* wr = (const f32x4*)&lw[co * 48];
    float s = bias[co];
#pragma unroll
    for (int q = 0; q < 12; ++q) {
      f32x4 wq = wr[q];
      s = fmaf(tvq[q][0], wq[0], s);
      s = fmaf(tvq[q][1], wq[1], s);
      s = fmaf(tvq[q][2], wq[2], s);
      s = fmaf(tvq[q][3], wq[3], s);
    }
    s = fmaxf(s, 0.f);
    if (co & 1) orow[co >> 1] = pack2(prev, s);
    else prev = s;
  }
}

// ========================= MFMA implicit GEMM ===============================
// MODE 0: conv3x3 (A [32768][256], N=256, K=9*256), optional res, optional f32 dup
// MODE 2: conv4x4 s2 (A [131072][128], N=256, K=16*128)
// MODE 3: convT2 per-parity (A [32768][256], N=128, K=4*256), scatter out
template<int MODE, int NSUB, int KIT, int AK, int KPN>
__global__ __launch_bounds__(256) void igemm_kernel(
    const short* __restrict__ Abuf, const short* __restrict__ Bw,
    const float* __restrict__ bias, const short* __restrict__ res,
    short* __restrict__ outb, float* __restrict__ outf32,
    const short* __restrict__ zerob, int po, int pq)
{
  __shared__ __align__(16) short Alds[2][2048];    // 2 x [64 rows][32 ci] bf16
  const int tid = threadIdx.x;
  const int wv = tid >> 6, l = tid & 63;
  const int lcol = l & 15, lk = l >> 4;
  const int m0 = blockIdx.x * 64;

  // staging role
  const int srow = tid >> 2;
  const int sm = m0 + srow;
  const int cchunk = (tid & 3) ^ (srow & 3);          // swizzled source chunk
  const int s_img = sm & ~255;
  const int s_h = (sm >> 4) & 15, s_w = sm & 15;
  const int s_b1024 = (sm >> 8) * 1024;
  short* stage_dst = &Alds[0][wv * 512];

  f32x4 acc[4][NSUB];
#pragma unroll
  for (int i = 0; i < 4; ++i)
#pragma unroll
    for (int j = 0; j < NSUB; ++j) acc[i][j] = (f32x4){0.f, 0.f, 0.f, 0.f};

  int boff[NSUB];
#pragma unroll
  for (int ns = 0; ns < NSUB; ++ns)
    boff[ns] = (wv * (NSUB * 16) + ns * 16 + lcol) * KPN + lk * 8;

  const int aoff_base = lcol * 32 + ((lk ^ (lcol & 3)) * 8);

  auto STAGE = [&](int it, int bufc) {
    int kk, ih, iw, srcrow; bool v;
    if constexpr (MODE == 0) {
      const int jj = it >> 3; kk = it & 7;
      const int q3 = jj / 3;
      ih = s_h + q3 - 1; iw = s_w + (jj - q3 * 3) - 1;
      v = ((unsigned)ih < 16u) & ((unsigned)iw < 16u);
      srcrow = s_img + ih * 16 + iw;
    } else if constexpr (MODE == 2) {
      const int jj = it >> 2; kk = it & 3;
      ih = 2 * s_h + (jj >> 2) - 1; iw = 2 * s_w + (jj & 3) - 1;
      v = ((unsigned)ih < 32u) & ((unsigned)iw < 32u);
      srcrow = s_b1024 + ih * 32 + iw;
    } else {
      const int jj = it >> 3; kk = it & 7;
      ih = s_h + po - (jj >> 1); iw = s_w + pq - (jj & 1);
      v = ((unsigned)ih < 16u) & ((unsigned)iw < 16u);
      srcrow = s_img + ih * 16 + iw;
    }
    const short* src = v ? (Abuf + (size_t)srcrow * AK + kk * 32 + cchunk * 8) : zerob;
    __builtin_amdgcn_global_load_lds(
        (const __attribute__((address_space(1))) void*)src,
        (__attribute__((address_space(3))) void*)(stage_dst + bufc * 2048),
        16, 0, 0);
  };

  auto COMPUTE = [&](int it, int bufc) {
    int uoff;
    if constexpr (MODE == 0)      uoff = (it >> 3) * 65536 + (it & 7) * 32;
    else if constexpr (MODE == 2) uoff = (it >> 2) * 32768 + (it & 3) * 32;
    else                          uoff = (it >> 3) * 32768 + (it & 7) * 32;
    s16x8 a[4], b[NSUB];
#pragma unroll
    for (int ms = 0; ms < 4; ++ms)
      a[ms] = *(const s16x8*)&Alds[bufc][aoff_base + ms * 512];
#pragma unroll
    for (int ns = 0; ns < NSUB; ++ns)
      b[ns] = *(const s16x8*)(Bw + uoff + boff[ns]);
#pragma unroll
    for (int ms = 0; ms < 4; ++ms)
#pragma unroll
      for (int ns = 0; ns < NSUB; ++ns)
        acc[ms][ns] = __builtin_amdgcn_mfma_f32_16x16x32_bf16(a[ms], b[ns], acc[ms][ns], 0, 0, 0);
  };

  STAGE(0, 0);
  for (int it = 0; it < KIT; it += 2) {
    __syncthreads();
    if (it + 1 < KIT) STAGE(it + 1, 1);
    COMPUTE(it, 0);
    __syncthreads();
    if (it + 2 < KIT) STAGE(it + 2, 0);
    COMPUTE(it + 1, 1);
  }

  // epilogue
  const int r4 = lk * 4;
#pragma unroll
  for (int ms = 0; ms < 4; ++ms) {
#pragma unroll
    for (int ns = 0; ns < NSUB; ++ns) {
      const int n_l = wv * (NSUB * 16) + ns * 16 + lcol;
      const float bi = bias[n_l];
#pragma unroll
      for (int e = 0; e < 4; ++e) {
        const int m = m0 + ms * 16 + r4 + e;
        float val = acc[ms][ns][e] + bi;
        if constexpr (MODE == 3) {
          val = fmaxf(val, 0.f);
          const int orow = (m & ~255) * 4 + (2 * ((m >> 4) & 15) + po) * 32 + (2 * (m & 15) + pq);
          outb[(size_t)orow * 128 + n_l] = f2bf(val);
        } else {
          if (res) val += bf2f(res[(size_t)m * 256 + n_l]);
          val = fmaxf(val, 0.f);
          outb[(size_t)m * 256 + n_l] = f2bf(val);
          if (outf32) outf32[(size_t)m * 256 + n_l] = val;
        }
      }
    }
  }
}

// ========================= VQ block (fp32, unchanged from passing round) ====
__global__ __launch_bounds__(256) void rownorm_kernel(
    const float* __restrict__ a, float* __restrict__ nrm, int rows)
{
  const int wv = threadIdx.x >> 6, lane = threadIdx.x & 63;
  const int r = blockIdx.x * 4 + wv;
  if (r >= rows) return;
  const float* p = a + (size_t)r * DC;
  float s = 0.f;
#pragma unroll
  for (int i = 0; i < 4; ++i) { float v = p[lane + 64 * i]; s = fmaf(v, v, s); }
#pragma unroll
  for (int o = 32; o > 0; o >>= 1) s += __shfl_xor(s, o);
  if (lane == 0) nrm[r] = s;
}

__global__ __launch_bounds__(256) void dist_kernel(
    const float* __restrict__ A, const float* __restrict__ Bc,
    const float* __restrict__ zn, const float* __restrict__ cn,
    float* __restrict__ D)
{
  __shared__ float As[32][66];
  __shared__ float Bs[32][66];
  const int tid = threadIdx.x;
  const int m0 = blockIdx.x * 64;
  const int n0 = blockIdx.y * 64;
  const int tm = tid >> 4, tn = tid & 15;
  float acc[4][4];
#pragma unroll
  for (int i = 0; i < 4; ++i)
#pragma unroll
    for (int j = 0; j < 4; ++j) acc[i][j] = 0.f;

  for (int k0 = 0; k0 < DC; k0 += 32) {
#pragma unroll
    for (int i = 0; i < 8; ++i) {
      const int idx = tid + i * 256;
      const int r = idx >> 5, kk = idx & 31;
      As[kk][r] = A[(size_t)(m0 + r) * DC + k0 + kk];
      Bs[kk][r] = Bc[(size_t)(n0 + r) * DC + k0 + kk];
    }
    __syncthreads();
#pragma unroll
    for (int kk = 0; kk < 32; ++kk) {
      float av[4], bv[4];
#pragma unroll
      for (int i = 0; i < 4; ++i) av[i] = As[kk][tm * 4 + i];
#pragma unroll
      for (int j = 0; j < 4; ++j) bv[j] = Bs[kk][tn * 4 + j];
#pragma unroll
      for (int i = 0; i < 4; ++i)
#pragma unroll
        for (int j = 0; j < 4; ++j) acc[i][j] = fmaf(av[i], bv[j], acc[i][j]);
    }
    __syncthreads();
  }
#pragma unroll
  for (int i = 0; i < 4; ++i) {
    const int m = m0 + tm * 4 + i;
    const float zni = zn[m];
#pragma unroll
    for (int j = 0; j < 4; ++j) {
      const int n = n0 + tn * 4 + j;
      D[(size_t)m * KCB + n] = zni + cn[n] - 2.f * acc[i][j];
    }
  }
}

__global__ void initq_kernel(const float* __restrict__ pi, float* __restrict__ logq,
                             float* __restrict__ qsum, float* __restrict__ Sacc)
{
  const int k = blockIdx.x * 256 + threadIdx.x;
  logq[k] = logf(fmaxf(pi[k], EPSQ));
  qsum[k] = 0.f;
  if (k == 0) *Sacc = 0.f;
}

__global__ __launch_bounds__(256) void ba_kernel(
    float* __restrict__ D, const float* __restrict__ logq,
    float* __restrict__ qsum, int* __restrict__ idxout, int storeP)
{
  __shared__ float qp[4][1024];
  const int tid = threadIdx.x;
  const int wv = tid >> 6, lane = tid & 63;
  for (int i = tid; i < 4096; i += 256) ((float*)qp)[i] = 0.f;
  __syncthreads();

  float lq[16];
#pragma unroll
  for (int it = 0; it < 16; ++it) lq[it] = logq[it * 64 + lane];

  const int n0 = blockIdx.x * 16;
  for (int rr = 0; rr < 4; ++rr) {
    const int n = n0 + wv * 4 + rr;
    float* drow = D + (size_t)n * KCB;
    float lfr[16];
    float mx = -1e30f;
#pragma unroll
    for (int it = 0; it < 16; ++it) {
      lfr[it] = lq[it] - BETA_F * drow[it * 64 + lane];
      mx = fmaxf(mx, lfr[it]);
    }
#pragma unroll
    for (int o = 32; o > 0; o >>= 1) mx = fmaxf(mx, __shfl_xor(mx, o));
    float e[16];
    float s = 0.f;
#pragma unroll
    for (int it = 0; it < 16; ++it) { e[it] = __expf(lfr[it] - mx); s += e[it]; }
#pragma unroll
    for (int o = 32; o > 0; o >>= 1) s += __shfl_xor(s, o);
    const float inv = 1.f / s;
#pragma unroll
    for (int it = 0; it < 16; ++it) qp[wv][it * 64 + lane] += e[it] * inv;

    if (storeP) {
#pragma unroll
      for (int it = 0; it < 16; ++it) drow[it * 64 + lane] = e[it] * inv;
      float bv = lfr[0]; int bi = lane;
#pragma unroll
      for (int it = 1; it < 16; ++it) {
        const int k = it * 64 + lane;
        if (lfr[it] > bv) { bv = lfr[it]; bi = k; }
      }
#pragma unroll
      for (int o = 32; o > 0; o >>= 1) {
        const float ov = __shfl_xor(bv, o);
        const int oi = __shfl_xor(bi, o);
        if (ov > bv || (ov == bv && oi < bi)) { bv = ov; bi = oi; }
      }
      if (lane == 0) idxout[n] = bi;
    }
  }
  __syncthreads();
  for (int k = tid; k < 1024; k += 256) {
    const float v = qp[0][k] + qp[1][k] + qp[2][k] + qp[3][k];
    atomicAdd(&qsum[k], v);
  }
}

__global__ void finalize_kernel(float* __restrict__ qsum, float* __restrict__ logq)
{
  const int k = blockIdx.x * 256 + threadIdx.x;
  const float q = fmaxf(qsum[k] * (1.f / 32768.f), EPSQ);
  logq[k] = logf(q);
  qsum[k] = 0.f;
}

__global__ __launch_bounds__(1024) void ent_kernel(
    const float* __restrict__ qsum, float* __restrict__ out_ent)
{
  const int k = threadIdx.x;
  const float q = fmaxf(qsum[k] * (1.f / 32768.f), EPSQ);
  float v = q * logf(q);
#pragma unroll
  for (int o = 32; o > 0; o >>= 1) v += __shfl_xor(v, o);
  __shared__ float red[16];
  const int wv = k >> 6, lane = k & 63;
  if (lane == 0) red[wv] = v;
  __syncthreads();
  if (k == 0) {
    float s = 0.f;
    for (int i = 0; i < 16; ++i) s += red[i];
    *out_ent = 0.01f * s;
  }
}

__global__ __launch_bounds__(256) void zqloss_kernel(
    const float* __restrict__ P, const float* __restrict__ cb,
    const float* __restrict__ zf, float* __restrict__ Sacc)
{
  __shared__ float As[32][66];
  __shared__ float Bs[32][66];
  __shared__ float red[4];
  const int tid = threadIdx.x;
  const int m0 = blockIdx.x * 64;
  const int n0 = blockIdx.y * 64;
  const int tm = tid >> 4, tn = tid & 15;
  float acc[4][4];
#pragma unroll
  for (int i = 0; i < 4; ++i)
#pragma unroll
    for (int j = 0; j < 4; ++j) acc[i][j] = 0.f;

  for (int k0 = 0; k0 < KCB; k0 += 32) {
#pragma unroll
    for (int i = 0; i < 8; ++i) {
      const int idx = tid + i * 256;
      { const int r = idx >> 5, kk = idx & 31;
        As[kk][r] = P[(size_t)(m0 + r) * KCB + k0 + kk]; }
      { const int c = idx & 63, kk = idx >> 6;
        Bs[kk][c] = cb[(size_t)(k0 + kk) * DC + n0 + c]; }
    }
    __syncthreads();
#pragma unroll
    for (int kk = 0; kk < 32; ++kk) {
      float av[4], bv[4];
#pragma unroll
      for (int i = 0; i < 4; ++i) av[i] = As[kk][tm * 4 + i];
#pragma unroll
      for (int j = 0; j < 4; ++j) bv[j] = Bs[kk][tn * 4 + j];
#pragma unroll
      for (int i = 0; i < 4; ++i)
#pragma unroll
        for (int j = 0; j < 4; ++j) acc[i][j] = fmaf(av[i], bv[j], acc[i][j]);
    }
    __syncthreads();
  }
  float ls = 0.f;
#pragma unroll
  for (int i = 0; i < 4; ++i) {
    const int m = m0 + tm * 4 + i;
#pragma unroll
    for (int j = 0; j < 4; ++j) {
      const int n = n0 + tn * 4 + j;
      const float d = acc[i][j] - zf[(size_t)m * DC + n];
      ls = fmaf(d, d, ls);
    }
  }
#pragma unroll
  for (int o = 32; o > 0; o >>= 1) ls += __shfl_xor(ls, o);
  const int wv = tid >> 6, lane = tid & 63;
  if (lane == 0) red[wv] = ls;
  __syncthreads();
  if (tid == 0) atomicAdd(Sacc, red[0] + red[1] + red[2] + red[3]);
}

__global__ void scalars_kernel(const float* __restrict__ S, float* __restrict__ out2)
{
  const float s = *S;
  out2[0] = 0.25f * s / 8388608.f;
  out2[1] = s / 8388608.f;
}

// zq_hard gather -> NHWC bf16 [32768][256]
__global__ void gather16_kernel(const int* __restrict__ idx, const short* __restrict__ cbb,
                                short* __restrict__ out)
{
  const int t = blockIdx.x * 256 + threadIdx.x;  // 2,097,152 threads of 4 elems
  const int m = t >> 6, d4 = (t & 63) * 4;
  *(s16x4*)(out + (size_t)m * 256 + d4) = *(const s16x4*)(cbb + (size_t)idx[m] * 256 + d4);
}

// ========================= convT3: 128->3, 32->64, direct ==================
__global__ __launch_bounds__(256) void convt3_kernel(
    const short* __restrict__ in, const float* __restrict__ w,
    const float* __restrict__ bias, float* __restrict__ out)
{
  __shared__ __align__(16) short li[100 * 136];
  __shared__ float lw[6144];
  const int tid = threadIdx.x;
  const int tile = blockIdx.x;          // 0..15
  const int b = blockIdx.y;
  const int ty0 = (tile >> 2) * 16, tx0 = (tile & 3) * 16;
  const int iy0 = (tile >> 2) * 8 - 1, ix0 = (tile & 3) * 8 - 1;
  // stage 100 pixels x 128 channels (16 chunks of 8)
  for (int s = tid; s < 1600; s += 256) {
    const int pix = s >> 4, ch = s & 15;
    const int r = pix / 10, c = pix - r * 10;
    const int ih = iy0 + r, iw = ix0 + c;
    s16x8 v = {0, 0, 0, 0, 0, 0, 0, 0};
    if ((unsigned)ih < 32u && (unsigned)iw < 32u)
      v = *(const s16x8*)(in + ((size_t)b * 1024 + ih * 32 + iw) * 128 + ch * 8);
    *(s16x8*)&li[pix * 136 + ch * 8] = v;
  }
  for (int s = tid; s < 6144; s += 256) lw[s] = w[s];
  __syncthreads();
  const int ty = tid >> 4, tx = tid & 15;
  const int oh2 = ty0 + ty, ow2 = tx0 + tx;
  const int kh0 = (oh2 + 1) & 1, kw0 = (ow2 + 1) & 1;
  const int ih0 = (oh2 + 1 - kh0) >> 1, iw0 = (ow2 + 1 - kw0) >> 1;
  const int rl0 = ih0 - iy0, cl0 = iw0 - ix0;
  const int p00 = rl0 * 10 + cl0, p01 = p00 - 1, p10 = p00 - 10, p11 = p00 - 11;
  const int wi00 = kh0 * 4 + kw0, wi01 = wi00 + 2, wi10 = wi00 + 8, wi11 = wi00 + 10;
  float acc0 = 0.f, acc1 = 0.f, acc2 = 0.f;
  for (int ch = 0; ch < 16; ++ch) {
    const s16x8 v00 = *(const s16x8*)&li[p00 * 136 + ch * 8];
    const s16x8 v01 = *(const s16x8*)&li[p01 * 136 + ch * 8];
    const s16x8 v10 = *(const s16x8*)&li[p10 * 136 + ch * 8];
    const s16x8 v11 = *(const s16x8*)&li[p11 * 136 + ch * 8];
#pragma unroll
    for (int e = 0; e < 8; ++e) {
      const int ci = ch * 8 + e;
      const float* wr = &lw[ci * 48];
      const float f00 = bf2f(v00[e]), f01 = bf2f(v01[e]);
      const float f10 = bf2f(v10[e]), f11 = bf2f(v11[e]);
      acc0 = fmaf(wr[wi00], f00, fmaf(wr[wi01], f01, fmaf(wr[wi10], f10, fmaf(wr[wi11], f11, acc0))));
      acc1 = fmaf(wr[16 + wi00], f00, fmaf(wr[16 + wi01], f01, fmaf(wr[16 + wi10], f10, fmaf(wr[16 + wi11], f11, acc1))));
      acc2 = fmaf(wr[32 + wi00], f00, fmaf(wr[32 + wi01], f01, fmaf(wr[32 + wi10], f10, fmaf(wr[32 + wi11], f11, acc2))));
    }
  }
  const size_t ob = ((size_t)(b * 3) * 64 + oh2) * 64 + ow2;
  out[ob] = acc0 + bias[0];
  out[ob + 4096] = acc1 + bias[1];
  out[ob + 8192] = acc2 + bias[2];
}

// =====================================================================
extern "C" void kernel_launch(void* const* d_in, const int* in_sizes, int n_in,
                              void* d_out, int out_size, void* d_ws, size_t ws_size,
                              hipStream_t stream)
{
  const float* x     = (const float*)d_in[0];
  const float* ew1   = (const float*)d_in[1];
  const float* eb1   = (const float*)d_in[2];
  const float* ew2   = (const float*)d_in[3];
  const float* eb2   = (const float*)d_in[4];
  const float* ew3   = (const float*)d_in[5];
  const float* eb3   = (const float*)d_in[6];
  const float* er1aw = (const float*)d_in[7];
  const float* er1ab = (const float*)d_in[8];
  const float* er1bw = (const float*)d_in[9];
  const float* er1bb = (const float*)d_in[10];
  const float* er2aw = (const float*)d_in[11];
  const float* er2ab = (const float*)d_in[12];
  const float* er2bw = (const float*)d_in[13];
  const float* er2bb = (const float*)d_in[14];
  const float* cb    = (const float*)d_in[15];
  const float* pi    = (const float*)d_in[16];
  const float* dr1aw = (const float*)d_in[17];
  const float* dr1ab = (const float*)d_in[18];
  const float* dr1bw = (const float*)d_in[19];
  const float* dr1bb = (const float*)d_in[20];
  const float* dr2aw = (const float*)d_in[21];
  const float* dr2ab = (const float*)d_in[22];
  const float* dr2bw = (const float*)d_in[23];
  const float* dr2bb = (const float*)d_in[24];
  const float* dw1   = (const float*)d_in[25];
  const float* db1   = (const float*)d_in[26];
  const float* dwt2  = (const float*)d_in[27];
  const float* dbt2  = (const float*)d_in[28];
  const float* dwt3  = (const float*)d_in[29];
  const float* dbt3  = (const float*)d_in[30];

  float* outf = (float*)d_out;

  // workspace layout (bytes), ~222.2 MB of 256 MiB
  char* W = (char*)d_ws;
  short* BIGA  = (short*)W;                    // 33,554,432 B: a1 bf16 -> ZF32 f32 -> convt2-out bf16
  float* ZF32  = (float*)W;
  float* DIST  = (float*)(W + 33554432);       // 134,217,728 B fp32 [32768][1024]
  short* X0    = (short*)(W + 167772160);      // 16,777,216 B each
  short* X1    = (short*)(W + 184549376);
  short* X2    = (short*)(W + 201326592);
  short* WT3   = (short*)(W + 218103808);      // 1,179,648 B (reused per conv3)
  short* WT2   = (short*)(W + 219283456);      // 1,048,576 B
  short* WTT2  = (short*)(W + 220332032);      // 1,048,576 B
  short* CBB   = (short*)(W + 221380608);      //   524,288 B
  float* zn    = (float*)(W + 221904896);
  float* cn    = (float*)(W + 222035968);
  float* qsum  = (float*)(W + 222040064);
  float* logq  = (float*)(W + 222044160);
  int*   idx   = (int*)(W + 222048256);
  float* Sacc  = (float*)(W + 222179328);
  short* zerob = (short*)(W + 222179344);

  const dim3 blk(256);
  #define IG3(A_, W_, B_, R_, O_, F_) \
    igemm_kernel<0,4,72,256,256><<<dim3(512), blk, 0, stream>>>(A_, W_, B_, R_, O_, F_, zerob, 0, 0)

  init0_kernel<<<dim3(1), dim3(64), 0, stream>>>(zerob);

  // -------- encoder --------
  conv1_kernel<<<dim3(4, NB), blk, 0, stream>>>(x, ew1, eb1, BIGA);
  w2t_kernel<<<dim3(2048), blk, 0, stream>>>(ew2, WT2);
  igemm_kernel<2,4,64,128,128><<<dim3(512), blk, 0, stream>>>(
      BIGA, WT2, eb2, nullptr, X0, nullptr, zerob, 0, 0);
  w3t_kernel<<<dim3(2304), blk, 0, stream>>>(ew3, WT3);
  IG3(X0, WT3, eb3, nullptr, X1, nullptr);                 // h3
  w3t_kernel<<<dim3(2304), blk, 0, stream>>>(er1aw, WT3);
  IG3(X1, WT3, er1ab, nullptr, X2, nullptr);
  w3t_kernel<<<dim3(2304), blk, 0, stream>>>(er1bw, WT3);
  IG3(X2, WT3, er1bb, X1, X0, nullptr);                    // h4
  w3t_kernel<<<dim3(2304), blk, 0, stream>>>(er2aw, WT3);
  IG3(X0, WT3, er2ab, nullptr, X1, nullptr);
  w3t_kernel<<<dim3(2304), blk, 0, stream>>>(er2bw, WT3);
  IG3(X1, WT3, er2bb, X0, X2, ZF32);                       // z (bf16 + fp32 dup)

  // -------- VQ / Blahut-Arimoto (fp32) --------
  rownorm_kernel<<<dim3(NROW / 4), blk, 0, stream>>>(ZF32, zn, NROW);
  rownorm_kernel<<<dim3(KCB / 4), blk, 0, stream>>>(cb, cn, KCB);
  initq_kernel<<<dim3(4), blk, 0, stream>>>(pi, logq, qsum, Sacc);
  dist_kernel<<<dim3(NROW / 64, KCB / 64), blk, 0, stream>>>(ZF32, cb, zn, cn, DIST);
  for (int i = 0; i < 5; ++i) {
    ba_kernel<<<dim3(NROW / 16), blk, 0, stream>>>(DIST, logq, qsum, idx, (i == 4) ? 1 : 0);
    if (i < 4) finalize_kernel<<<dim3(4), blk, 0, stream>>>(qsum, logq);
  }
  ent_kernel<<<dim3(1), dim3(1024), 0, stream>>>(qsum, outf + 1572866);
  zqloss_kernel<<<dim3(NROW / 64, DC / 64), blk, 0, stream>>>(DIST, cb, ZF32, Sacc);
  scalars_kernel<<<dim3(1), dim3(1), 0, stream>>>(Sacc, outf + 1572864);
  cbbf_kernel<<<dim3(1024), blk, 0, stream>>>(cb, CBB);
  gather16_kernel<<<dim3(8192), blk, 0, stream>>>(idx, CBB, X0);  // zq_hard NHWC bf16

  // -------- decoder --------
  w3t_kernel<<<dim3(2304), blk, 0, stream>>>(dr1aw, WT3);
  IG3(X0, WT3, dr1ab, nullptr, X1, nullptr);
  w3t_kernel<<<dim3(2304), blk, 0, stream>>>(dr1bw, WT3);
  IG3(X1, WT3, dr1bb, X0, X2, nullptr);                    // y1
  w3t_kernel<<<dim3(2304), blk, 0, stream>>>(dr2aw, WT3);
  IG3(X2, WT3, dr2ab, nullptr, X0, nullptr);
  w3t_kernel<<<dim3(2304), blk, 0, stream>>>(dr2bw, WT3);
  IG3(X0, WT3, dr2bb, X2, X1, nullptr);                    // y2
  w3t_kernel<<<dim3(2304), blk, 0, stream>>>(dw1, WT3);
  IG3(X1, WT3, db1, nullptr, X0, nullptr);                 // y3
  wtt2_kernel<<<dim3(2048), blk, 0, stream>>>(dwt2, WTT2);
  for (int p = 0; p < 4; ++p)
    igemm_kernel<3,2,32,256,256><<<dim3(512), blk, 0, stream>>>(
        X0, WTT2 + p * 131072, dbt2, nullptr, BIGA, nullptr, zerob, p >> 1, p & 1);
  convt3_kernel<<<dim3(16, NB), blk, 0, stream>>>(BIGA, dwt3, dbt3, outf);
  #undef IG3
}

// Round 5
// 1715.871 us; speedup vs baseline: 6.2340x; 1.2829x over previous
//
#include <hip/hip_runtime.h>
#include <math.h>

// ---------------- problem constants ----------------
#define NB   128
#define DC   256
#define SP   256
#define NROW 32768
#define KCB  1024
#define BETA_F 0.1f
#define EPSQ 1e-10f

typedef __attribute__((ext_vector_type(8))) short s16x8;
typedef __attribute__((ext_vector_type(4))) short s16x4;
typedef __attribute__((ext_vector_type(4))) float f32x4;

__device__ __forceinline__ short f2bf(float f) {
  unsigned u = __builtin_bit_cast(unsigned, f);
  unsigned r = (u + 0x7FFFu + ((u >> 16) & 1u)) >> 16;
  return (short)r;
}
__device__ __forceinline__ float bf2f(short s) {
  unsigned u = ((unsigned)(unsigned short)s) << 16;
  return __builtin_bit_cast(float, u);
}
__device__ __forceinline__ unsigned pack2(float a, float b) {
  return (unsigned)(unsigned short)f2bf(a) | ((unsigned)(unsigned short)f2bf(b) << 16);
}

// ========================= init: zero the zero-source buffer ===============
__global__ void init0_kernel(short* __restrict__ zerob)
{
  if (threadIdx.x < 8) zerob[threadIdx.x] = 0;
}

// ========================= weight transposes (fp32 -> bf16) =================
// conv3x3 [256co][256ci][3][3] -> [9][256co][256ci]
__global__ void w3t_kernel(const float* __restrict__ w, short* __restrict__ o)
{
  const int i = blockIdx.x * 256 + threadIdx.x;  // 589824
  const int ci = i & 255, co = (i >> 8) & 255, j = i >> 16;
  o[i] = f2bf(w[((size_t)(co * 256 + ci)) * 9 + j]);
}
// conv2 4x4 [256co][128ci][16] -> [16][256co][128ci]
__global__ void w2t_kernel(const float* __restrict__ w, short* __restrict__ o)
{
  const int i = blockIdx.x * 256 + threadIdx.x;  // 524288
  const int ci = i & 127, co = (i >> 7) & 255, j = i >> 15;
  o[i] = f2bf(w[((size_t)(co * 128 + ci)) * 16 + j]);
}
// convt2 [256ci][128co][4][4] -> [4 parity][4 tap][128co][256ci]
__global__ void wtt2_kernel(const float* __restrict__ w, short* __restrict__ o)
{
  const int i = blockIdx.x * 256 + threadIdx.x;  // 524288
  const int ci = i & 255, co = (i >> 8) & 127, j = (i >> 15) & 3, p = i >> 17;
  const int po = p >> 1, pq = p & 1, a = j >> 1, b2 = j & 1;
  const int kh = (1 - po) + 2 * a, kw = (1 - pq) + 2 * b2;
  o[i] = f2bf(w[((size_t)(ci * 128 + co)) * 16 + kh * 4 + kw]);
}
// codebook fp32 -> bf16 [1024][256]
__global__ void cbbf_kernel(const float* __restrict__ cb, short* __restrict__ o)
{
  const int i = blockIdx.x * 256 + threadIdx.x;  // 262144
  o[i] = f2bf(cb[i]);
}
// codebook transpose fp32 -> bf16 [256][1024]
__global__ void cbt_kernel(const float* __restrict__ cb, short* __restrict__ o)
{
  const int i = blockIdx.x * 256 + threadIdx.x;  // 262144
  const int d = i >> 10, k = i & 1023;
  o[i] = f2bf(cb[(size_t)k * 256 + d]);
}

// ========================= conv1: 3->128, 4x4 s2, 64->32, out NHWC bf16 =====
__global__ __launch_bounds__(256) void conv1_kernel(
    const float* __restrict__ x, const float* __restrict__ w,
    const float* __restrict__ bias, short* __restrict__ out)
{
  __shared__ float li[3][34][34];
  __shared__ __align__(16) float lw[6144];
  const int tid = threadIdx.x;
  const int tile = blockIdx.x;          // 0..3 quadrant of 32x32 output
  const int b = blockIdx.y;
  const int qy = tile >> 1, qx = tile & 1;
  const int ihlo = qy * 32 - 1, iwlo = qx * 32 - 1;
  for (int ci = 0; ci < 3; ++ci)
    for (int s = tid; s < 1156; s += 256) {
      const int r = s / 34, c = s - r * 34;
      const int ih = ihlo + r, iw = iwlo + c;
      float v = 0.f;
      if ((unsigned)ih < 64u && (unsigned)iw < 64u)
        v = x[((size_t)(b * 3 + ci) * 64 + ih) * 64 + iw];
      li[ci][r][c] = v;
    }
  for (int s = tid; s < 6144; s += 256) lw[s] = w[s];
  __syncthreads();
  const int ty = tid >> 4, tx = tid & 15;
  f32x4 tvq[12];
#pragma unroll
  for (int ci = 0; ci < 3; ++ci)
#pragma unroll
    for (int kh = 0; kh < 4; ++kh)
#pragma unroll
      for (int kw = 0; kw < 4; ++kw)
        tvq[ci * 4 + kh][kw] = li[ci][2 * ty + kh][2 * tx + kw];
  const int oh = qy * 16 + ty, ow = qx * 16 + tx;
  unsigned* orow = (unsigned*)(out + ((size_t)b * 1024 + oh * 32 + ow) * 128);
  float prev = 0.f;
  for (int co = 0; co < 128; ++co) {
    const f32x4* wr = (const f32x4*)&lw[co * 48];
    float s = bias[co];
#pragma unroll
    for (int q = 0; q < 12; ++q) {
      f32x4 wq = wr[q];
      s = fmaf(tvq[q][0], wq[0], s);
      s = fmaf(tvq[q][1], wq[1], s);
      s = fmaf(tvq[q][2], wq[2], s);
      s = fmaf(tvq[q][3], wq[3], s);
    }
    s = fmaxf(s, 0.f);
    if (co & 1) orow[co >> 1] = pack2(prev, s);
    else prev = s;
  }
}

// ========================= MFMA implicit GEMM ===============================
// MODE 0: conv3x3 (A [32768][256], N=256, K=9*256), optional res, optional f32 dup
// MODE 2: conv4x4 s2 (A [131072][128], N=256, K=16*128)
// MODE 3: convT2 per-parity (A [32768][256], N=128, K=4*256), scatter out
// MODE 4: distance variant (A=zf [32768][256], B=cb [1024][256], grid.y=4,
//         out DV[m][1024] bf16 = cn[n] - 2*acc; bias arg = cn)
template<int MODE, int NSUB, int KIT, int AK, int KPN>
__global__ __launch_bounds__(256) void igemm_kernel(
    const short* __restrict__ Abuf, const short* __restrict__ Bw,
    const float* __restrict__ bias, const short* __restrict__ res,
    short* __restrict__ outb, float* __restrict__ outf32,
    const short* __restrict__ zerob, int po, int pq)
{
  __shared__ __align__(16) short Alds[2][2048];    // 2 x [64 rows][32 ci] bf16
  const int tid = threadIdx.x;
  const int wv = tid >> 6, l = tid & 63;
  const int lcol = l & 15, lk = l >> 4;
  const int m0 = blockIdx.x * 64;

  // staging role
  const int srow = tid >> 2;
  const int sm = m0 + srow;
  const int cchunk = (tid & 3) ^ (srow & 3);          // swizzled source chunk
  const int s_img = sm & ~255;
  const int s_h = (sm >> 4) & 15, s_w = sm & 15;
  const int s_b1024 = (sm >> 8) * 1024;
  short* stage_dst = &Alds[0][wv * 512];

  const short* Bp = Bw;
  if constexpr (MODE == 4) Bp += (size_t)blockIdx.y * 65536;  // 256 rows x 256 k

  f32x4 acc[4][NSUB];
#pragma unroll
  for (int i = 0; i < 4; ++i)
#pragma unroll
    for (int j = 0; j < NSUB; ++j) acc[i][j] = (f32x4){0.f, 0.f, 0.f, 0.f};

  int boff[NSUB];
#pragma unroll
  for (int ns = 0; ns < NSUB; ++ns)
    boff[ns] = (wv * (NSUB * 16) + ns * 16 + lcol) * KPN + lk * 8;

  const int aoff_base = lcol * 32 + ((lk ^ (lcol & 3)) * 8);

  auto STAGE = [&](int it, int bufc) {
    int kk, ih, iw, srcrow; bool v;
    if constexpr (MODE == 0) {
      const int jj = it >> 3; kk = it & 7;
      const int q3 = jj / 3;
      ih = s_h + q3 - 1; iw = s_w + (jj - q3 * 3) - 1;
      v = ((unsigned)ih < 16u) & ((unsigned)iw < 16u);
      srcrow = s_img + ih * 16 + iw;
    } else if constexpr (MODE == 2) {
      const int jj = it >> 2; kk = it & 3;
      ih = 2 * s_h + (jj >> 2) - 1; iw = 2 * s_w + (jj & 3) - 1;
      v = ((unsigned)ih < 32u) & ((unsigned)iw < 32u);
      srcrow = s_b1024 + ih * 32 + iw;
    } else if constexpr (MODE == 4) {
      kk = it; v = true; srcrow = sm;
    } else {
      const int jj = it >> 3; kk = it & 7;
      ih = s_h + po - (jj >> 1); iw = s_w + pq - (jj & 1);
      v = ((unsigned)ih < 16u) & ((unsigned)iw < 16u);
      srcrow = s_img + ih * 16 + iw;
    }
    const short* src = v ? (Abuf + (size_t)srcrow * AK + kk * 32 + cchunk * 8) : zerob;
    __builtin_amdgcn_global_load_lds(
        (const __attribute__((address_space(1))) void*)src,
        (__attribute__((address_space(3))) void*)(stage_dst + bufc * 2048),
        16, 0, 0);
  };

  auto COMPUTE = [&](int it, int bufc) {
    int uoff;
    if constexpr (MODE == 0)      uoff = (it >> 3) * 65536 + (it & 7) * 32;
    else if constexpr (MODE == 2) uoff = (it >> 2) * 32768 + (it & 3) * 32;
    else if constexpr (MODE == 4) uoff = it * 32;
    else                          uoff = (it >> 3) * 32768 + (it & 7) * 32;
    s16x8 a[4], b[NSUB];
#pragma unroll
    for (int ms = 0; ms < 4; ++ms)
      a[ms] = *(const s16x8*)&Alds[bufc][aoff_base + ms * 512];
#pragma unroll
    for (int ns = 0; ns < NSUB; ++ns)
      b[ns] = *(const s16x8*)(Bp + uoff + boff[ns]);
#pragma unroll
    for (int ms = 0; ms < 4; ++ms)
#pragma unroll
      for (int ns = 0; ns < NSUB; ++ns)
        acc[ms][ns] = __builtin_amdgcn_mfma_f32_16x16x32_bf16(a[ms], b[ns], acc[ms][ns], 0, 0, 0);
  };

  STAGE(0, 0);
  for (int it = 0; it < KIT; it += 2) {
    __syncthreads();
    if (it + 1 < KIT) STAGE(it + 1, 1);
    COMPUTE(it, 0);
    __syncthreads();
    if (it + 2 < KIT) STAGE(it + 2, 0);
    COMPUTE(it + 1, 1);
  }

  // epilogue
  const int r4 = lk * 4;
#pragma unroll
  for (int ms = 0; ms < 4; ++ms) {
#pragma unroll
    for (int ns = 0; ns < NSUB; ++ns) {
      const int n_l = wv * (NSUB * 16) + ns * 16 + lcol;
#pragma unroll
      for (int e = 0; e < 4; ++e) {
        const int m = m0 + ms * 16 + r4 + e;
        if constexpr (MODE == 4) {
          const int n_g = blockIdx.y * 256 + n_l;
          const float val = bias[n_g] - 2.f * acc[ms][ns][e];
          outb[(size_t)m * 1024 + n_g] = f2bf(val);
        } else {
          float val = acc[ms][ns][e] + bias[n_l];
          if constexpr (MODE == 3) {
            val = fmaxf(val, 0.f);
            const int orow = (m & ~255) * 4 + (2 * ((m >> 4) & 15) + po) * 32 + (2 * (m & 15) + pq);
            outb[(size_t)orow * 128 + n_l] = f2bf(val);
          } else {
            if (res) val += bf2f(res[(size_t)m * 256 + n_l]);
            val = fmaxf(val, 0.f);
            outb[(size_t)m * 256 + n_l] = f2bf(val);
            if (outf32) outf32[(size_t)m * 256 + n_l] = val;
          }
        }
      }
    }
  }
}

// ========================= VQ block =========================================
// cn rownorm (codebook only)
__global__ __launch_bounds__(256) void rownorm_kernel(
    const float* __restrict__ a, float* __restrict__ nrm, int rows)
{
  const int wv = threadIdx.x >> 6, lane = threadIdx.x & 63;
  const int r = blockIdx.x * 4 + wv;
  if (r >= rows) return;
  const float* p = a + (size_t)r * DC;
  float s = 0.f;
#pragma unroll
  for (int i = 0; i < 4; ++i) { float v = p[lane + 64 * i]; s = fmaf(v, v, s); }
#pragma unroll
  for (int o = 32; o > 0; o >>= 1) s += __shfl_xor(s, o);
  if (lane == 0) nrm[r] = s;
}

__global__ void initq_kernel(const float* __restrict__ pi, float* __restrict__ logq,
                             float* __restrict__ qsum, float* __restrict__ Sacc)
{
  const int k = blockIdx.x * 256 + threadIdx.x;
  logq[k] = logf(fmaxf(pi[k], EPSQ));
  qsum[k] = 0.f;
  if (k == 0) *Sacc = 0.f;
}

// one BA iteration over bf16 DV (row-constant-free distances).
// 4 waves, 4 rows/wave (16 rows/block), grid 2048. storeP: pack P bf16 in-place.
__global__ __launch_bounds__(256) void ba2_kernel(
    unsigned* __restrict__ DV, const float* __restrict__ logq,
    float* __restrict__ qsum, int* __restrict__ idxout, int storeP)
{
  __shared__ float qp[4][1024];
  const int tid = threadIdx.x;
  const int wv = tid >> 6, lane = tid & 63;
  for (int i = tid; i < 4096; i += 256) ((float*)qp)[i] = 0.f;
  __syncthreads();

  float2 lq[8];
#pragma unroll
  for (int it = 0; it < 8; ++it) lq[it] = *(const float2*)&logq[it * 128 + lane * 2];

  const int n0 = blockIdx.x * 16;
  for (int rr = 0; rr < 4; ++rr) {
    const int n = n0 + wv * 4 + rr;
    unsigned* rowp = DV + (size_t)n * 512;
    float l0[8], l1[8];
    float mx = -1e30f;
#pragma unroll
    for (int it = 0; it < 8; ++it) {
      const unsigned w = rowp[it * 64 + lane];
      l0[it] = lq[it].x - BETA_F * bf2f((short)(w & 0xFFFFu));
      l1[it] = lq[it].y - BETA_F * bf2f((short)(w >> 16));
      mx = fmaxf(mx, fmaxf(l0[it], l1[it]));
    }
#pragma unroll
    for (int o = 32; o > 0; o >>= 1) mx = fmaxf(mx, __shfl_xor(mx, o));
    float e0[8], e1[8];
    float s = 0.f;
#pragma unroll
    for (int it = 0; it < 8; ++it) {
      e0[it] = __expf(l0[it] - mx);
      e1[it] = __expf(l1[it] - mx);
      s += e0[it] + e1[it];
    }
#pragma unroll
    for (int o = 32; o > 0; o >>= 1) s += __shfl_xor(s, o);
    const float inv = 1.f / s;
#pragma unroll
    for (int it = 0; it < 8; ++it) {
      qp[wv][it * 128 + lane * 2]     += e0[it] * inv;
      qp[wv][it * 128 + lane * 2 + 1] += e1[it] * inv;
    }

    if (storeP) {
#pragma unroll
      for (int it = 0; it < 8; ++it)
        rowp[it * 64 + lane] = pack2(e0[it] * inv, e1[it] * inv);
      // argmax of logits == argmax of P; first index on ties
      float bv = l0[0]; int bi = lane * 2;
      if (l1[0] > bv) { bv = l1[0]; bi = lane * 2 + 1; }
#pragma unroll
      for (int it = 1; it < 8; ++it) {
        const int k = it * 128 + lane * 2;
        if (l0[it] > bv) { bv = l0[it]; bi = k; }
        if (l1[it] > bv) { bv = l1[it]; bi = k + 1; }
      }
#pragma unroll
      for (int o = 32; o > 0; o >>= 1) {
        const float ov = __shfl_xor(bv, o);
        const int oi = __shfl_xor(bi, o);
        if (ov > bv || (ov == bv && oi < bi)) { bv = ov; bi = oi; }
      }
      if (lane == 0) idxout[n] = bi;
    }
  }
  __syncthreads();
  for (int k = tid; k < 1024; k += 256) {
    const float v = qp[0][k] + qp[1][k] + qp[2][k] + qp[3][k];
    atomicAdd(&qsum[k], v);
  }
}

__global__ void finalize_kernel(float* __restrict__ qsum, float* __restrict__ logq)
{
  const int k = blockIdx.x * 256 + threadIdx.x;
  const float q = fmaxf(qsum[k] * (1.f / 32768.f), EPSQ);
  logq[k] = logf(q);
  qsum[k] = 0.f;
}

__global__ __launch_bounds__(1024) void ent_kernel(
    const float* __restrict__ qsum, float* __restrict__ out_ent)
{
  const int k = threadIdx.x;
  const float q = fmaxf(qsum[k] * (1.f / 32768.f), EPSQ);
  float v = q * logf(q);
#pragma unroll
  for (int o = 32; o > 0; o >>= 1) v += __shfl_xor(v, o);
  __shared__ float red[16];
  const int wv = k >> 6, lane = k & 63;
  if (lane == 0) red[wv] = v;
  __syncthreads();
  if (k == 0) {
    float s = 0.f;
    for (int i = 0; i < 16; ++i) s += red[i];
    *out_ent = 0.01f * s;
  }
}

// zq_soft = P @ cbT via MFMA (P bf16 [32768][1024], CBT [256][1024]);
// fused sum((zq_soft - zf)^2) into Sacc. grid 512, 64 rows/block.
__global__ __launch_bounds__(256) void pvq_kernel(
    const short* __restrict__ P, const short* __restrict__ CBT,
    const float* __restrict__ zf32, float* __restrict__ Sacc)
{
  __shared__ __align__(16) short Alds[2][2048];
  __shared__ float red[4];
  const int tid = threadIdx.x;
  const int wv = tid >> 6, l = tid & 63;
  const int lcol = l & 15, lk = l >> 4;
  const int m0 = blockIdx.x * 64;

  const int srow = tid >> 2;
  const int cchunk = (tid & 3) ^ (srow & 3);
  short* stage_dst = &Alds[0][wv * 512];

  f32x4 acc[4][4];
#pragma unroll
  for (int i = 0; i < 4; ++i)
#pragma unroll
    for (int j = 0; j < 4; ++j) acc[i][j] = (f32x4){0.f, 0.f, 0.f, 0.f};

  int boff[4];
#pragma unroll
  for (int ns = 0; ns < 4; ++ns)
    boff[ns] = (wv * 64 + ns * 16 + lcol) * 1024 + lk * 8;

  const int aoff_base = lcol * 32 + ((lk ^ (lcol & 3)) * 8);

  auto STAGE = [&](int it, int bufc) {
    const short* src = P + (size_t)(m0 + srow) * 1024 + it * 32 + cchunk * 8;
    __builtin_amdgcn_global_load_lds(
        (const __attribute__((address_space(1))) void*)src,
        (__attribute__((address_space(3))) void*)(stage_dst + bufc * 2048),
        16, 0, 0);
  };
  auto COMPUTE = [&](int it, int bufc) {
    s16x8 a[4], b[4];
#pragma unroll
    for (int ms = 0; ms < 4; ++ms)
      a[ms] = *(const s16x8*)&Alds[bufc][aoff_base + ms * 512];
#pragma unroll
    for (int ns = 0; ns < 4; ++ns)
      b[ns] = *(const s16x8*)(CBT + it * 32 + boff[ns]);
#pragma unroll
    for (int ms = 0; ms < 4; ++ms)
#pragma unroll
      for (int ns = 0; ns < 4; ++ns)
        acc[ms][ns] = __builtin_amdgcn_mfma_f32_16x16x32_bf16(a[ms], b[ns], acc[ms][ns], 0, 0, 0);
  };

  STAGE(0, 0);
  for (int it = 0; it < 32; it += 2) {
    __syncthreads();
    if (it + 1 < 32) STAGE(it + 1, 1);
    COMPUTE(it, 0);
    __syncthreads();
    if (it + 2 < 32) STAGE(it + 2, 0);
    COMPUTE(it + 1, 1);
  }

  float ls = 0.f;
  const int r4 = lk * 4;
#pragma unroll
  for (int ms = 0; ms < 4; ++ms) {
#pragma unroll
    for (int ns = 0; ns < 4; ++ns) {
      const int n_l = wv * 64 + ns * 16 + lcol;
#pragma unroll
      for (int e = 0; e < 4; ++e) {
        const int m = m0 + ms * 16 + r4 + e;
        const float d = acc[ms][ns][e] - zf32[(size_t)m * 256 + n_l];
        ls = fmaf(d, d, ls);
      }
    }
  }
#pragma unroll
  for (int o = 32; o > 0; o >>= 1) ls += __shfl_xor(ls, o);
  if (l == 0) red[wv] = ls;
  __syncthreads();
  if (tid == 0) atomicAdd(Sacc, red[0] + red[1] + red[2] + red[3]);
}

__global__ void scalars_kernel(const float* __restrict__ S, float* __restrict__ out2)
{
  const float s = *S;
  out2[0] = 0.25f * s / 8388608.f;
  out2[1] = s / 8388608.f;
}

// zq_hard gather -> NHWC bf16 [32768][256]
__global__ void gather16_kernel(const int* __restrict__ idx, const short* __restrict__ cbb,
                                short* __restrict__ out)
{
  const int t = blockIdx.x * 256 + threadIdx.x;  // 2,097,152 threads of 4 elems
  const int m = t >> 6, d4 = (t & 63) * 4;
  *(s16x4*)(out + (size_t)m * 256 + d4) = *(const s16x4*)(cbb + (size_t)idx[m] * 256 + d4);
}

// ========================= convT3: 128->3, 32->64, direct ==================
__global__ __launch_bounds__(256) void convt3_kernel(
    const short* __restrict__ in, const float* __restrict__ w,
    const float* __restrict__ bias, float* __restrict__ out)
{
  __shared__ __align__(16) short li[100 * 136];
  __shared__ float lw[6144];
  const int tid = threadIdx.x;
  const int tile = blockIdx.x;          // 0..15
  const int b = blockIdx.y;
  const int ty0 = (tile >> 2) * 16, tx0 = (tile & 3) * 16;
  const int iy0 = (tile >> 2) * 8 - 1, ix0 = (tile & 3) * 8 - 1;
  for (int s = tid; s < 1600; s += 256) {
    const int pix = s >> 4, ch = s & 15;
    const int r = pix / 10, c = pix - r * 10;
    const int ih = iy0 + r, iw = ix0 + c;
    s16x8 v = {0, 0, 0, 0, 0, 0, 0, 0};
    if ((unsigned)ih < 32u && (unsigned)iw < 32u)
      v = *(const s16x8*)(in + ((size_t)b * 1024 + ih * 32 + iw) * 128 + ch * 8);
    *(s16x8*)&li[pix * 136 + ch * 8] = v;
  }
  for (int s = tid; s < 6144; s += 256) lw[s] = w[s];
  __syncthreads();
  const int ty = tid >> 4, tx = tid & 15;
  const int oh2 = ty0 + ty, ow2 = tx0 + tx;
  const int kh0 = (oh2 + 1) & 1, kw0 = (ow2 + 1) & 1;
  const int ih0 = (oh2 + 1 - kh0) >> 1, iw0 = (ow2 + 1 - kw0) >> 1;
  const int rl0 = ih0 - iy0, cl0 = iw0 - ix0;
  const int p00 = rl0 * 10 + cl0, p01 = p00 - 1, p10 = p00 - 10, p11 = p00 - 11;
  const int wi00 = kh0 * 4 + kw0, wi01 = wi00 + 2, wi10 = wi00 + 8, wi11 = wi00 + 10;
  float acc0 = 0.f, acc1 = 0.f, acc2 = 0.f;
  for (int ch = 0; ch < 16; ++ch) {
    const s16x8 v00 = *(const s16x8*)&li[p00 * 136 + ch * 8];
    const s16x8 v01 = *(const s16x8*)&li[p01 * 136 + ch * 8];
    const s16x8 v10 = *(const s16x8*)&li[p10 * 136 + ch * 8];
    const s16x8 v11 = *(const s16x8*)&li[p11 * 136 + ch * 8];
#pragma unroll
    for (int e = 0; e < 8; ++e) {
      const int ci = ch * 8 + e;
      const float* wr = &lw[ci * 48];
      const float f00 = bf2f(v00[e]), f01 = bf2f(v01[e]);
      const float f10 = bf2f(v10[e]), f11 = bf2f(v11[e]);
      acc0 = fmaf(wr[wi00], f00, fmaf(wr[wi01], f01, fmaf(wr[wi10], f10, fmaf(wr[wi11], f11, acc0))));
      acc1 = fmaf(wr[16 + wi00], f00, fmaf(wr[16 + wi01], f01, fmaf(wr[16 + wi10], f10, fmaf(wr[16 + wi11], f11, acc1))));
      acc2 = fmaf(wr[32 + wi00], f00, fmaf(wr[32 + wi01], f01, fmaf(wr[32 + wi10], f10, fmaf(wr[32 + wi11], f11, acc2))));
    }
  }
  const size_t ob = ((size_t)(b * 3) * 64 + oh2) * 64 + ow2;
  out[ob] = acc0 + bias[0];
  out[ob + 4096] = acc1 + bias[1];
  out[ob + 8192] = acc2 + bias[2];
}

// =====================================================================
extern "C" void kernel_launch(void* const* d_in, const int* in_sizes, int n_in,
                              void* d_out, int out_size, void* d_ws, size_t ws_size,
                              hipStream_t stream)
{
  const float* x     = (const float*)d_in[0];
  const float* ew1   = (const float*)d_in[1];
  const float* eb1   = (const float*)d_in[2];
  const float* ew2   = (const float*)d_in[3];
  const float* eb2   = (const float*)d_in[4];
  const float* ew3   = (const float*)d_in[5];
  const float* eb3   = (const float*)d_in[6];
  const float* er1aw = (const float*)d_in[7];
  const float* er1ab = (const float*)d_in[8];
  const float* er1bw = (const float*)d_in[9];
  const float* er1bb = (const float*)d_in[10];
  const float* er2aw = (const float*)d_in[11];
  const float* er2ab = (const float*)d_in[12];
  const float* er2bw = (const float*)d_in[13];
  const float* er2bb = (const float*)d_in[14];
  const float* cb    = (const float*)d_in[15];
  const float* pi    = (const float*)d_in[16];
  const float* dr1aw = (const float*)d_in[17];
  const float* dr1ab = (const float*)d_in[18];
  const float* dr1bw = (const float*)d_in[19];
  const float* dr1bb = (const float*)d_in[20];
  const float* dr2aw = (const float*)d_in[21];
  const float* dr2ab = (const float*)d_in[22];
  const float* dr2bw = (const float*)d_in[23];
  const float* dr2bb = (const float*)d_in[24];
  const float* dw1   = (const float*)d_in[25];
  const float* db1   = (const float*)d_in[26];
  const float* dwt2  = (const float*)d_in[27];
  const float* dbt2  = (const float*)d_in[28];
  const float* dwt3  = (const float*)d_in[29];
  const float* dbt3  = (const float*)d_in[30];

  float* outf = (float*)d_out;

  // workspace layout (bytes), ~156 MB of 256 MiB
  char* W = (char*)d_ws;
  short* BIGA  = (short*)W;                    // 33.5MB: conv1-out -> ZF32 -> convt2-out
  float* ZF32  = (float*)W;
  short* DV    = (short*)(W + 33554432);       // 67MB bf16 [32768][1024]: dv -> P
  short* X0    = (short*)(W + 100663296);      // 16.7MB each
  short* X1    = (short*)(W + 117440512);
  short* X2    = (short*)(W + 134217728);
  short* WT3   = (short*)(W + 150994944);      // 1,179,648 B
  short* WT2   = (short*)(W + 152174592);      // 1,048,576 B
  short* WTT2  = (short*)(W + 153223168);      // 1,048,576 B
  short* CBB   = (short*)(W + 154271744);      //   524,288 B
  short* CBT   = (short*)(W + 154796032);      //   524,288 B
  float* cn    = (float*)(W + 155320320);      //     4,096 B
  float* qsum  = (float*)(W + 155324416);
  float* logq  = (float*)(W + 155328512);
  int*   idx   = (int*)(W + 155332608);        //   131,072 B
  float* Sacc  = (float*)(W + 155463680);
  short* zerob = (short*)(W + 155463696);

  const dim3 blk(256);
  #define IG3(A_, W_, B_, R_, O_, F_) \
    igemm_kernel<0,4,72,256,256><<<dim3(512), blk, 0, stream>>>(A_, W_, B_, R_, O_, F_, zerob, 0, 0)

  init0_kernel<<<dim3(1), dim3(64), 0, stream>>>(zerob);

  // -------- encoder --------
  conv1_kernel<<<dim3(4, NB), blk, 0, stream>>>(x, ew1, eb1, BIGA);
  w2t_kernel<<<dim3(2048), blk, 0, stream>>>(ew2, WT2);
  igemm_kernel<2,4,64,128,128><<<dim3(512), blk, 0, stream>>>(
      BIGA, WT2, eb2, nullptr, X0, nullptr, zerob, 0, 0);
  w3t_kernel<<<dim3(2304), blk, 0, stream>>>(ew3, WT3);
  IG3(X0, WT3, eb3, nullptr, X1, nullptr);                 // h3
  w3t_kernel<<<dim3(2304), blk, 0, stream>>>(er1aw, WT3);
  IG3(X1, WT3, er1ab, nullptr, X2, nullptr);
  w3t_kernel<<<dim3(2304), blk, 0, stream>>>(er1bw, WT3);
  IG3(X2, WT3, er1bb, X1, X0, nullptr);                    // h4
  w3t_kernel<<<dim3(2304), blk, 0, stream>>>(er2aw, WT3);
  IG3(X0, WT3, er2ab, nullptr, X1, nullptr);
  w3t_kernel<<<dim3(2304), blk, 0, stream>>>(er2bw, WT3);
  IG3(X1, WT3, er2bb, X0, X2, ZF32);                       // z (bf16 + fp32 dup)

  // -------- VQ / Blahut-Arimoto --------
  rownorm_kernel<<<dim3(KCB / 4), blk, 0, stream>>>(cb, cn, KCB);
  cbbf_kernel<<<dim3(1024), blk, 0, stream>>>(cb, CBB);
  cbt_kernel<<<dim3(1024), blk, 0, stream>>>(cb, CBT);
  initq_kernel<<<dim3(4), blk, 0, stream>>>(pi, logq, qsum, Sacc);
  // DV[m][n] = cn[n] - 2*zf.cb  (bf16, row-constant-free distances)
  igemm_kernel<4,4,8,256,256><<<dim3(512, 4), blk, 0, stream>>>(
      X2, CBB, cn, nullptr, DV, nullptr, zerob, 0, 0);
  for (int i = 0; i < 5; ++i) {
    ba2_kernel<<<dim3(NROW / 16), blk, 0, stream>>>(
        (unsigned*)DV, logq, qsum, idx, (i == 4) ? 1 : 0);
    if (i < 4) finalize_kernel<<<dim3(4), blk, 0, stream>>>(qsum, logq);
  }
  ent_kernel<<<dim3(1), dim3(1024), 0, stream>>>(qsum, outf + 1572866);
  pvq_kernel<<<dim3(512), blk, 0, stream>>>(DV, CBT, ZF32, Sacc);
  scalars_kernel<<<dim3(1), dim3(1), 0, stream>>>(Sacc, outf + 1572864);
  gather16_kernel<<<dim3(8192), blk, 0, stream>>>(idx, CBB, X0);  // zq_hard NHWC bf16

  // -------- decoder --------
  w3t_kernel<<<dim3(2304), blk, 0, stream>>>(dr1aw, WT3);
  IG3(X0, WT3, dr1ab, nullptr, X1, nullptr);
  w3t_kernel<<<dim3(2304), blk, 0, stream>>>(dr1bw, WT3);
  IG3(X1, WT3, dr1bb, X0, X2, nullptr);                    // y1
  w3t_kernel<<<dim3(2304), blk, 0, stream>>>(dr2aw, WT3);
  IG3(X2, WT3, dr2ab, nullptr, X0, nullptr);
  w3t_kernel<<<dim3(2304), blk, 0, stream>>>(dr2bw, WT3);
  IG3(X0, WT3, dr2bb, X2, X1, nullptr);                    // y2
  w3t_kernel<<<dim3(2304), blk, 0, stream>>>(dw1, WT3);
  IG3(X1, WT3, db1, nullptr, X0, nullptr);                 // y3
  wtt2_kernel<<<dim3(2048), blk, 0, stream>>>(dwt2, WTT2);
  for (int p = 0; p < 4; ++p)
    igemm_kernel<3,2,32,256,256><<<dim3(512), blk, 0, stream>>>(
        X0, WTT2 + p * 131072, dbt2, nullptr, BIGA, nullptr, zerob, p >> 1, p & 1);
  convt3_kernel<<<dim3(16, NB), blk, 0, stream>>>(BIGA, dwt3, dbt3, outf);
  #undef IG3
}